// Round 10
// baseline (1533.342 us; speedup 1.0000x reference)
//
#include <hip/hip_runtime.h>

#define TT 1024
#define HH 128

typedef unsigned int u32;
typedef unsigned short u16;
typedef _Float16 f16;
typedef f16 f16x2 __attribute__((ext_vector_type(2)));
typedef f16 f16x8 __attribute__((ext_vector_type(8)));
typedef float f32x4 __attribute__((ext_vector_type(4)));
typedef u32 u32x4 __attribute__((ext_vector_type(4)));

#define MFMA16(A, B, C) __builtin_amdgcn_mfma_f32_16x16x32_f16((A), (B), (C), 0, 0, 0)
#define K2L2E 2.8853900817779268f   /* 2*log2(e) */

__device__ __forceinline__ float ex2(float x) {
#if __has_builtin(__builtin_amdgcn_exp2f)
    return __builtin_amdgcn_exp2f(x);
#else
    extern "C" __device__ float __ocml_exp2_f32(float);
    return __ocml_exp2_f32(x);
#endif
}
__device__ __forceinline__ float rcp_(float x) { return __builtin_amdgcn_rcpf(x); }

__device__ __forceinline__ float fdot2_(u32 w, u32 h, float acc) {
#if __has_builtin(__builtin_amdgcn_fdot2)
    return __builtin_amdgcn_fdot2(__builtin_bit_cast(f16x2, w),
                                  __builtin_bit_cast(f16x2, h), acc, false);
#else
    const f16x2 a = __builtin_bit_cast(f16x2, w);
    const f16x2 b = __builtin_bit_cast(f16x2, h);
    return fmaf((float)a.y, (float)b.y, fmaf((float)a.x, (float)b.x, acc));
#endif
}

__device__ __forceinline__ float dpp_mov(float v, const int ctrl) {
    int t;
    switch (ctrl) {   // quad_perm broadcasts (R6-R9 verified)
      case 0x00: t = __builtin_amdgcn_update_dpp(0, __float_as_int(v), 0x00, 0xF, 0xF, true); break;
      case 0x55: t = __builtin_amdgcn_update_dpp(0, __float_as_int(v), 0x55, 0xF, 0xF, true); break;
      case 0xAA: t = __builtin_amdgcn_update_dpp(0, __float_as_int(v), 0xAA, 0xF, 0xF, true); break;
      default:   t = __builtin_amdgcn_update_dpp(0, __float_as_int(v), 0xFF, 0xF, 0xF, true); break;
    }
    return __int_as_float(t);
}
__device__ __forceinline__ float dpp_add(float v, const int ctrl) {
    int t;
    switch (ctrl) {
      case 0xB1:  t = __builtin_amdgcn_update_dpp(0, __float_as_int(v), 0xB1,  0xF, 0xF, true); break;
      case 0x4E:  t = __builtin_amdgcn_update_dpp(0, __float_as_int(v), 0x4E,  0xF, 0xF, true); break;
      default:    t = __builtin_amdgcn_update_dpp(0, __float_as_int(v), 0x141, 0xF, 0xF, true); break;
    }
    return v + __int_as_float(t);
}
__device__ __forceinline__ float red8(float v) {
    v = dpp_add(v, 0xB1); v = dpp_add(v, 0x4E); v = dpp_add(v, 0x141);
    return v;
}

// ---------------- prep (identical to R9-verified) ---------------------------
__global__ void prep(const float* __restrict__ Whh0, const float* __restrict__ Whh1,
                     const float* __restrict__ Wih1, const float* __restrict__ Wih0,
                     const float* __restrict__ bih0, const float* __restrict__ bhh0,
                     const float* __restrict__ bih1, const float* __restrict__ bhh1,
                     f16* __restrict__ Wpk0, f16* __restrict__ Wpk1,
                     f16* __restrict__ W1h,  f16* __restrict__ W1l,
                     float* __restrict__ bx0, float* __restrict__ wx0,
                     float* __restrict__ b1p)
{
    const int p = blockIdx.x;       // 0..511
    const int k = threadIdx.x;      // 0..127
    const int c = p & 3, u = p >> 2;
    const int g = c * 128 + u;
    const float sc = (c == 2) ? K2L2E : -1.4426950408889634f;

    Wpk0[p * HH + k] = (f16)(Whh0[(size_t)g * HH + k] * sc);
    Wpk1[p * HH + k] = (f16)(Whh1[(size_t)g * HH + k] * sc);
    const float wf = Wih1[(size_t)g * HH + k] * sc;
    const f16 wh = (f16)wf;
    W1h[p * HH + k] = wh;
    W1l[p * HH + k] = (f16)(wf - (float)wh);
    if (k == 0) {
        bx0[p] = (bih0[g] + bhh0[g]) * sc;
        wx0[p] = Wih0[g] * sc;
        b1p[p] = (bih1[g] + bhh1[g]) * sc;
    }
}

// ============================ fused 2-layer LSTM + FC =======================
// 256 blocks (1 batch row), 512 threads, 1 block/CU. Layer1 lags layer0 by one
// 32-step chunk; both rec cores run in the same step loop (2x ILP), 1 barrier
// per step. h0 handoff via LDS chunk buffer; per-chunk MFMA input projection.
__global__ __launch_bounds__(512, 1) void lstm_fused(
    const float* __restrict__ x,
    const f16* __restrict__ Wpk0, const float* __restrict__ bx0,
    const float* __restrict__ wx0, const f16* __restrict__ Wpk1,
    const f16* __restrict__ W1h,  const f16* __restrict__ W1l,
    const float* __restrict__ b1p, const float* __restrict__ fcw,
    const float* __restrict__ fcb, float* __restrict__ out)
{
    const int b = blockIdx.x;
    const int tid = threadIdx.x;
    const int u = tid >> 2;
    const int wv = tid >> 6, lane = tid & 63;
    const int lr = lane & 15, lq = lane >> 4;
    const bool lead = (tid & 3) == 0;
    const bool is_g = (tid & 3) == 2;
    const float Ag = is_g ? -2.f : 1.f;
    const float Cg = is_g ?  1.f : 0.f;

    __shared__ __align__(16) float xS[TT];          // 4 KB
    __shared__ __align__(16) float xgS[32 * 512];   // 64 KB
    __shared__ __align__(16) u16 h0c[32][HH];       // 8 KB (XOR-swizzled rows)
    __shared__ __align__(16) u32 hS0[2][64];        // packed f16 h, layer 0
    __shared__ __align__(16) u32 hS1[2][64];        // packed f16 h, layer 1

    xS[tid]       = x[(size_t)b * TT + tid];
    xS[tid + 512] = x[(size_t)b * TT + tid + 512];
    if (tid < 64) { hS0[0][tid] = 0u; hS0[1][tid] = 0u; hS1[0][tid] = 0u; hS1[1][tid] = 0u; }

    // both layers' recurrent weights, register-resident (128 packed u32)
    u32x4 W0[16], W1r[16];
    {
        const u32* wp0 = (const u32*)(Wpk0 + (size_t)tid * HH);
        const u32* wp1 = (const u32*)(Wpk1 + (size_t)tid * HH);
#pragma unroll
        for (int r = 0; r < 16; ++r) {
            W0[r]  = *(const u32x4*)(wp0 + r * 4);
            W1r[r] = *(const u32x4*)(wp1 + r * 4);
        }
    }
    const float biasx = bx0[tid];
    const float wxv   = wx0[tid];
    const float2 fc2  = *(const float2*)&fcw[2 * lane];   // used by wave 7
    const float fcbv  = fcb[0];
    const int bp_addr = ((lane ^ 32) << 2);
    float c0 = 0.f, c1 = 0.f;
    float* ob = out + (size_t)b * TT;
    __syncthreads();

#pragma unroll 1
    for (int cc = 0; cc < 33; ++cc) {
        const bool l0act = cc < 32;
        const bool l1act = cc > 0;
        const int t0 = cc * 32;

#pragma unroll 1
        for (int i = 0; i < 32; ++i) {
            const int cur = i & 1, nxt = cur ^ 1;
            const int t1 = t0 - 32 + i;     // layer-1 global step

            // ---- FC for layer-1 step t1-1 (wave 7 only, one step behind) ----
            if (l1act && wv == 7 && t1 > 0) {
                const f16x2 hp = __builtin_bit_cast(f16x2, hS1[cur][lane]);
                float pf = fmaf((float)hp.y, fc2.y, (float)hp.x * fc2.x);
                pf = red8(pf);
                pf += __int_as_float(__builtin_amdgcn_ds_swizzle(__float_as_int(pf), 0x201F)); // xor8
                pf += __int_as_float(__builtin_amdgcn_ds_swizzle(__float_as_int(pf), 0x401F)); // xor16
                pf += __int_as_float(__builtin_amdgcn_ds_bpermute(bp_addr, __float_as_int(pf))); // xor32
                if (lane == 0) ob[t1 - 1] = pf + fcbv;
            }

            // ---- layer 0 step t0+i ----
            float h0v = 0.f;
            if (l0act) {
                const u32* hcur = hS0[cur];
                float a0 = 0.f, a1 = 0.f, a2 = 0.f, a3 = 0.f;
#pragma unroll
                for (int r = 0; r < 16; ++r) {
                    const u32x4 hq = *(const u32x4*)(hcur + r * 4);
                    a0 = fdot2_(W0[r].x, hq.x, a0);
                    a1 = fdot2_(W0[r].y, hq.y, a1);
                    a2 = fdot2_(W0[r].z, hq.z, a2);
                    a3 = fdot2_(W0[r].w, hq.w, a3);
                }
                const float a = (a0 + a1) + (a2 + a3) + fmaf(xS[t0 + i], wxv, biasx);
                const float act = fmaf(Ag, rcp_(1.f + ex2(a)), Cg);
                const float gi = dpp_mov(act, 0x00);
                const float gf = dpp_mov(act, 0x55);
                const float gg = dpp_mov(act, 0xAA);
                const float go = dpp_mov(act, 0xFF);
                c0 = fmaf(gf, c0, gi * gg);
                h0v = go * fmaf(-2.f, rcp_(1.f + ex2(K2L2E * c0)), 1.f);
            }

            // ---- layer 1 step t1 ----
            float h1v = 0.f;
            if (l1act) {
                const float xgv = xgS[i * 512 + (tid ^ ((i & 7) << 2))];
                const u32* hcur = hS1[cur];
                float a0 = 0.f, a1 = 0.f, a2 = 0.f, a3 = 0.f;
#pragma unroll
                for (int r = 0; r < 16; ++r) {
                    const u32x4 hq = *(const u32x4*)(hcur + r * 4);
                    a0 = fdot2_(W1r[r].x, hq.x, a0);
                    a1 = fdot2_(W1r[r].y, hq.y, a1);
                    a2 = fdot2_(W1r[r].z, hq.z, a2);
                    a3 = fdot2_(W1r[r].w, hq.w, a3);
                }
                const float a = (a0 + a1) + (a2 + a3) + xgv;
                const float act = fmaf(Ag, rcp_(1.f + ex2(a)), Cg);
                const float gi = dpp_mov(act, 0x00);
                const float gf = dpp_mov(act, 0x55);
                const float gg = dpp_mov(act, 0xAA);
                const float go = dpp_mov(act, 0xFF);
                c1 = fmaf(gf, c1, gi * gg);
                h1v = go * fmaf(-2.f, rcp_(1.f + ex2(K2L2E * c1)), 1.f);
            }

            // ---- state writes ----
            if (l0act && lead) {
                const u16 hb = __builtin_bit_cast(u16, (f16)h0v);
                ((u16*)hS0[nxt])[u] = hb;
                h0c[i][u ^ ((i & 7) << 3)] = hb;
            }
            if (l1act && lead)
                ((u16*)hS1[nxt])[u] = __builtin_bit_cast(u16, (f16)h1v);
            __syncthreads();
        }

        // ---- proj for chunk cc: xgS = W_ih1(permuted,split) @ h0c^T ----
        if (l0act) {
            f16x8 B0[4], B1[4];
#pragma unroll
            for (int ks = 0; ks < 4; ++ks) {
                const int kb = (ks * 32 + lq * 8) ^ ((lr & 7) << 3);
                B0[ks] = *(const f16x8*)&h0c[lr][kb];
                B1[ks] = *(const f16x8*)&h0c[16 + lr][kb];
            }
#pragma unroll
            for (int gtl = 0; gtl < 4; ++gtl) {
                const int g16 = (wv * 4 + gtl) * 16;
                const float4 bi = *(const float4*)&b1p[g16 + lq * 4];
                f32x4 a0 = {bi.x, bi.y, bi.z, bi.w};
                f32x4 a1 = a0;
#pragma unroll
                for (int ks = 0; ks < 4; ++ks) {
                    const f16x8 Ah = *(const f16x8*)(W1h + (size_t)(g16 + lr) * HH + ks * 32 + lq * 8);
                    const f16x8 Al = *(const f16x8*)(W1l + (size_t)(g16 + lr) * HH + ks * 32 + lq * 8);
                    a0 = MFMA16(Ah, B0[ks], a0);
                    a0 = MFMA16(Al, B0[ks], a0);
                    a1 = MFMA16(Ah, B1[ks], a1);
                    a1 = MFMA16(Al, B1[ks], a1);
                }
                const int gb = g16 + lq * 4;        // lane cols; rows lr / 16+lr
                *(f32x4*)&xgS[lr * 512 + (gb ^ ((lr & 7) << 2))] = a0;
                *(f32x4*)&xgS[(16 + lr) * 512 + (gb ^ ((lr & 7) << 2))] = a1;
            }
        }
        __syncthreads();
    }

    // ---- final FC for t = TT-1 (h_{1023} sits in hS1[0]) ----
    if (wv == 7) {
        const f16x2 hp = __builtin_bit_cast(f16x2, hS1[0][lane]);
        float pf = fmaf((float)hp.y, fc2.y, (float)hp.x * fc2.x);
        pf = red8(pf);
        pf += __int_as_float(__builtin_amdgcn_ds_swizzle(__float_as_int(pf), 0x201F));
        pf += __int_as_float(__builtin_amdgcn_ds_swizzle(__float_as_int(pf), 0x401F));
        pf += __int_as_float(__builtin_amdgcn_ds_bpermute(bp_addr, __float_as_int(pf)));
        if (lane == 0) ob[TT - 1] = pf + fcbv;
    }
}

extern "C" void kernel_launch(void* const* d_in, const int* in_sizes, int n_in,
                              void* d_out, int out_size, void* d_ws, size_t ws_size,
                              hipStream_t stream)
{
    const float* x    = (const float*)d_in[0];
    const float* Wih0 = (const float*)d_in[1];
    const float* Whh0 = (const float*)d_in[2];
    const float* bih0 = (const float*)d_in[3];
    const float* bhh0 = (const float*)d_in[4];
    const float* Wih1 = (const float*)d_in[5];
    const float* Whh1 = (const float*)d_in[6];
    const float* bih1 = (const float*)d_in[7];
    const float* bhh1 = (const float*)d_in[8];
    const float* fcw  = (const float*)d_in[9];
    const float* fcb  = (const float*)d_in[10];
    float* out = (float*)d_out;

    f16* Wpk0 = (f16*)d_ws;                 // 128 KiB each
    f16* Wpk1 = Wpk0 + 512 * HH;
    f16* W1h  = Wpk1 + 512 * HH;
    f16* W1l  = W1h + 512 * HH;
    float* bx0 = (float*)(W1l + 512 * HH);
    float* wx0 = bx0 + 512;
    float* b1p = wx0 + 512;

    prep<<<512, 128, 0, stream>>>(Whh0, Whh1, Wih1, Wih0, bih0, bhh0, bih1, bhh1,
                                  Wpk0, Wpk1, W1h, W1l, bx0, wx0, b1p);
    lstm_fused<<<256, 512, 0, stream>>>(x, Wpk0, bx0, wx0, Wpk1, W1h, W1l, b1p,
                                        fcw, fcb, out);
}

// Round 11
// 1269.413 us; speedup vs baseline: 1.2079x; 1.2079x over previous
//
#include <hip/hip_runtime.h>

#define TT 1024
#define HH 128

typedef unsigned int u32;
typedef unsigned short u16;
typedef _Float16 f16;
typedef f16 f16x2 __attribute__((ext_vector_type(2)));
typedef f16 f16x8 __attribute__((ext_vector_type(8)));
typedef float f32x4 __attribute__((ext_vector_type(4)));
typedef u32 u32x4 __attribute__((ext_vector_type(4)));

#define MFMA16(A, B, C) __builtin_amdgcn_mfma_f32_16x16x32_f16((A), (B), (C), 0, 0, 0)
#define K2L2E 2.8853900817779268f   /* 2*log2(e) */

__device__ __forceinline__ float ex2(float x) {
#if __has_builtin(__builtin_amdgcn_exp2f)
    return __builtin_amdgcn_exp2f(x);
#else
    extern "C" __device__ float __ocml_exp2_f32(float);
    return __ocml_exp2_f32(x);
#endif
}
__device__ __forceinline__ float rcp_(float x) { return __builtin_amdgcn_rcpf(x); }

__device__ __forceinline__ float fdot2_(u32 w, u32 h, float acc) {
#if __has_builtin(__builtin_amdgcn_fdot2)
    return __builtin_amdgcn_fdot2(__builtin_bit_cast(f16x2, w),
                                  __builtin_bit_cast(f16x2, h), acc, false);
#else
    const f16x2 a = __builtin_bit_cast(f16x2, w);
    const f16x2 b = __builtin_bit_cast(f16x2, h);
    return fmaf((float)a.y, (float)b.y, fmaf((float)a.x, (float)b.x, acc));
#endif
}

__device__ __forceinline__ float dpp_mov(float v, const int ctrl) {
    int t;
    switch (ctrl) {   // quad_perm patterns (R6-R9 verified)
      case 0x00: t = __builtin_amdgcn_update_dpp(0, __float_as_int(v), 0x00, 0xF, 0xF, true); break;
      case 0x55: t = __builtin_amdgcn_update_dpp(0, __float_as_int(v), 0x55, 0xF, 0xF, true); break;
      case 0xAA: t = __builtin_amdgcn_update_dpp(0, __float_as_int(v), 0xAA, 0xF, 0xF, true); break;
      case 0xFF: t = __builtin_amdgcn_update_dpp(0, __float_as_int(v), 0xFF, 0xF, 0xF, true); break;
      case 0xB1: t = __builtin_amdgcn_update_dpp(0, __float_as_int(v), 0xB1, 0xF, 0xF, true); break;
      default:   t = __builtin_amdgcn_update_dpp(0, __float_as_int(v), 0x4E, 0xF, 0xF, true); break;
    }
    return __int_as_float(t);
}
__device__ __forceinline__ float dpp_add(float v, const int ctrl) {
    int t;
    switch (ctrl) {
      case 0xB1:  t = __builtin_amdgcn_update_dpp(0, __float_as_int(v), 0xB1,  0xF, 0xF, true); break;
      case 0x4E:  t = __builtin_amdgcn_update_dpp(0, __float_as_int(v), 0x4E,  0xF, 0xF, true); break;
      case 0x141: t = __builtin_amdgcn_update_dpp(0, __float_as_int(v), 0x141, 0xF, 0xF, true); break;
      default:    t = __builtin_amdgcn_update_dpp(0, __float_as_int(v), 0x140, 0xF, 0xF, true); break;
    }
    return v + __int_as_float(t);
}

// swizzled LDS u32 index for logical h u32 index iu (block-rotation, bank-safe)
__device__ __forceinline__ int hswz(int iu) {
    return (iu & 0x30) + (((((iu >> 2) & 3) + (iu >> 4)) & 3) << 2) + (iu & 3);
}

// 4x4 transpose-reduce within a quad: inputs acc[c] = gate c partial over
// K-quarter q; output = gate (c=q) summed over all 4 quarters. Desk-checked.
__device__ __forceinline__ float xpose4(float a0, float a1, float a2, float a3, int q) {
    const bool qb0 = (q & 1) != 0;
    float s0, s1;
    {   // xor1: keep gates with c&1 == q&1
        const float send = qb0 ? a0 : a1;
        s0 = (qb0 ? a1 : a0) + dpp_mov(send, 0xB1);      // gate (q&1)
    }
    {
        const float send = qb0 ? a2 : a3;
        s1 = (qb0 ? a3 : a2) + dpp_mov(send, 0xB1);      // gate 2+(q&1)
    }
    const bool qb1 = (q & 2) != 0;
    const float send = qb1 ? s0 : s1;
    return (qb1 ? s1 : s0) + dpp_mov(send, 0x4E);        // gate q
}

// ---------------- prep (identical to R9-verified) ---------------------------
__global__ void prep(const float* __restrict__ Whh0, const float* __restrict__ Whh1,
                     const float* __restrict__ Wih1, const float* __restrict__ Wih0,
                     const float* __restrict__ bih0, const float* __restrict__ bhh0,
                     const float* __restrict__ bih1, const float* __restrict__ bhh1,
                     f16* __restrict__ Wpk0, f16* __restrict__ Wpk1,
                     f16* __restrict__ W1h,  f16* __restrict__ W1l,
                     float* __restrict__ bx0, float* __restrict__ wx0,
                     float* __restrict__ b1p)
{
    const int p = blockIdx.x;       // 0..511
    const int k = threadIdx.x;      // 0..127
    const int c = p & 3, u = p >> 2;
    const int g = c * 128 + u;
    const float sc = (c == 2) ? K2L2E : -1.4426950408889634f;

    Wpk0[p * HH + k] = (f16)(Whh0[(size_t)g * HH + k] * sc);
    Wpk1[p * HH + k] = (f16)(Whh1[(size_t)g * HH + k] * sc);
    const float wf = Wih1[(size_t)g * HH + k] * sc;
    const f16 wh = (f16)wf;
    W1h[p * HH + k] = wh;
    W1l[p * HH + k] = (f16)(wf - (float)wh);
    if (k == 0) {
        bx0[p] = (bih0[g] + bhh0[g]) * sc;
        wx0[p] = Wih0[g] * sc;
        b1p[p] = (bih1[g] + bhh1[g]) * sc;
    }
}

// ============================ layer 0 =======================================
// 256 blocks (1 batch row), 512 threads. Thread = (unit u=tid>>2, quad slot
// q=tid&3): ALL 4 gates of u over K-quarter q -> 64 packed weight u32 in VGPRs,
// only 4 ds_read_b128 of h per step. DPP transpose-reduce -> lane q holds gate
// q; quad broadcasts unchanged. h LDS block-rotated (bank-conflict-free).
__global__ __launch_bounds__(512, 2) void lstm0(
    const float* __restrict__ x, const f16* __restrict__ Wpk0,
    const float* __restrict__ bx0, const float* __restrict__ wx0,
    f16* __restrict__ h0g)
{
    const int b = blockIdx.x;
    const int tid = threadIdx.x;
    const int u = tid >> 2, q = tid & 3;
    const bool is_g = (q == 2);
    const float Ag = is_g ? -2.f : 1.f;
    const float Cg = is_g ?  1.f : 0.f;

    __shared__ __align__(16) float xS[TT];          // 4 KB
    __shared__ __align__(16) u32 hS[2][64];         // packed f16 h, swizzled
    __shared__ __align__(16) u16 hO[32][HH];        // 8 KB chunk staging

    xS[tid]       = x[(size_t)b * TT + tid];
    xS[tid + 512] = x[(size_t)b * TT + tid + 512];
    if (tid < 128) ((u32*)hS)[tid] = 0u;

    // weights: Wq[c][rb] covers gate (4u+c), k in [32q+8rb, 32q+8rb+8)
    u32x4 Wq[4][4];
#pragma unroll
    for (int c = 0; c < 4; ++c) {
        const u32* wp = (const u32*)Wpk0 + (size_t)((tid & ~3) + c) * 64 + q * 16;
#pragma unroll
        for (int rb = 0; rb < 4; ++rb) Wq[c][rb] = *(const u32x4*)(wp + rb * 4);
    }
    const float biasx = bx0[tid];
    const float wxv   = wx0[tid];
    float c1 = 0.f;
    __syncthreads();

    f16* og = h0g + (size_t)b * TT * HH;

#pragma unroll 1
    for (int t = 0; t < TT; ++t) {
        const u32* hcur = hS[t & 1];
        float a0 = 0.f, a1 = 0.f, a2 = 0.f, a3 = 0.f;
#pragma unroll
        for (int rb = 0; rb < 4; ++rb) {
            const u32x4 hq = *(const u32x4*)(hcur + (q << 4) + (((rb + q) & 3) << 2));
            a0 = fdot2_(Wq[0][rb].x, hq.x, a0); a0 = fdot2_(Wq[0][rb].y, hq.y, a0);
            a0 = fdot2_(Wq[0][rb].z, hq.z, a0); a0 = fdot2_(Wq[0][rb].w, hq.w, a0);
            a1 = fdot2_(Wq[1][rb].x, hq.x, a1); a1 = fdot2_(Wq[1][rb].y, hq.y, a1);
            a1 = fdot2_(Wq[1][rb].z, hq.z, a1); a1 = fdot2_(Wq[1][rb].w, hq.w, a1);
            a2 = fdot2_(Wq[2][rb].x, hq.x, a2); a2 = fdot2_(Wq[2][rb].y, hq.y, a2);
            a2 = fdot2_(Wq[2][rb].z, hq.z, a2); a2 = fdot2_(Wq[2][rb].w, hq.w, a2);
            a3 = fdot2_(Wq[3][rb].x, hq.x, a3); a3 = fdot2_(Wq[3][rb].y, hq.y, a3);
            a3 = fdot2_(Wq[3][rb].z, hq.z, a3); a3 = fdot2_(Wq[3][rb].w, hq.w, a3);
        }
        const float V = xpose4(a0, a1, a2, a3, q);
        const float a = V + fmaf(xS[t], wxv, biasx);
        const float act = fmaf(Ag, rcp_(1.f + ex2(a)), Cg);
        const float gi = dpp_mov(act, 0x00);
        const float gf = dpp_mov(act, 0x55);
        const float gg = dpp_mov(act, 0xAA);
        const float go = dpp_mov(act, 0xFF);
        c1 = fmaf(gf, c1, gi * gg);
        const float h = go * fmaf(-2.f, rcp_(1.f + ex2(K2L2E * c1)), 1.f);
        if (q == 0) {
            const u16 hb = __builtin_bit_cast(u16, (f16)h);
            ((u16*)hS[(t + 1) & 1])[2 * hswz(u >> 1) + (u & 1)] = hb;
            hO[t & 31][u] = hb;
        }
        __syncthreads();
        if ((t & 31) == 31) {   // coalesced chunk dump of h0 (f16 hi parts)
            *(u32x4*)((u16*)og + (size_t)(t - 31) * HH + tid * 8) =
                *(const u32x4*)(&hO[0][0] + tid * 8);
            __syncthreads();
        }
    }
}

// ============================ layer 1 + FC ==================================
// Same K-quarter rec core. Per chunk: MFMA input proj (R9-verified) -> xgS;
// 32 steps; FC = 4 DPP row-adds + 1 xor16 swizzle, 2 partials/wave/step,
// cross-wave gather once per chunk (no serial LDS chain, no tail case).
__global__ __launch_bounds__(512, 2) void lstm1(
    const f16* __restrict__ h0g, const f16* __restrict__ Wpk1,
    const f16* __restrict__ W1h, const f16* __restrict__ W1l,
    const float* __restrict__ b1p, const float* __restrict__ fcw,
    const float* __restrict__ fcb, float* __restrict__ out)
{
    const int b = blockIdx.x;
    const int tid = threadIdx.x;
    const int u = tid >> 2, q = tid & 3;
    const int wv = tid >> 6, lane = tid & 63;
    const int lr = lane & 15, lq = lane >> 4;
    const bool is_g = (q == 2);
    const float Ag = is_g ? -2.f : 1.f;
    const float Cg = is_g ?  1.f : 0.f;

    __shared__ __align__(16) float xgS[32 * 512];   // 64 KB (row-XOR swizzled)
    __shared__ __align__(16) u32 hS1[2][64];        // packed f16 h, swizzled
    __shared__ __align__(16) float fcP[32][16];     // 2 KB step partials

    if (tid < 128) ((u32*)hS1)[tid] = 0u;
    const float fcu025 = fcw[u] * 0.25f;            // quad-redundancy factor
    const float fcbv = fcb[0];
    float c1 = 0.f;
    __syncthreads();

    const f16* hb0 = h0g + (size_t)b * TT * HH;
    float* ob = out + (size_t)b * TT;

#pragma unroll 1
    for (int t0 = 0; t0 < TT; t0 += 32) {
        // ---- proj: xgS = W_ih1(permuted,split) @ h0^T + bias (R9-verified) ----
        {
            f16x8 B0[4], B1[4];
#pragma unroll
            for (int ks = 0; ks < 4; ++ks) {
                B0[ks] = *(const f16x8*)(hb0 + (size_t)(t0 + lr) * HH + ks * 32 + lq * 8);
                B1[ks] = *(const f16x8*)(hb0 + (size_t)(t0 + 16 + lr) * HH + ks * 32 + lq * 8);
            }
#pragma unroll
            for (int gtl = 0; gtl < 4; ++gtl) {
                const int g16 = (wv * 4 + gtl) * 16;
                const float4 bi = *(const float4*)&b1p[g16 + lq * 4];
                f32x4 a0 = {bi.x, bi.y, bi.z, bi.w};
                f32x4 a1 = a0;
#pragma unroll
                for (int ks = 0; ks < 4; ++ks) {
                    const f16x8 Ah = *(const f16x8*)(W1h + (size_t)(g16 + lr) * HH + ks * 32 + lq * 8);
                    const f16x8 Al = *(const f16x8*)(W1l + (size_t)(g16 + lr) * HH + ks * 32 + lq * 8);
                    a0 = MFMA16(Ah, B0[ks], a0);
                    a0 = MFMA16(Al, B0[ks], a0);
                    a1 = MFMA16(Ah, B1[ks], a1);
                    a1 = MFMA16(Al, B1[ks], a1);
                }
                const int gb = g16 + lq * 4;
                *(f32x4*)&xgS[lr * 512 + (gb ^ ((lr & 7) << 2))] = a0;
                *(f32x4*)&xgS[(16 + lr) * 512 + (gb ^ ((lr & 7) << 2))] = a1;
            }
        }
        __syncthreads();

        // reload rec weights after proj (R9 pattern: proj phase gets free regs)
        u32x4 Wq[4][4];
        {
            const u32* wb = (const u32*)Wpk1;
            asm volatile("" : "+v"(wb));
#pragma unroll
            for (int c = 0; c < 4; ++c) {
                const u32* wp = wb + (size_t)((tid & ~3) + c) * 64 + q * 16;
#pragma unroll
                for (int rb = 0; rb < 4; ++rb) Wq[c][rb] = *(const u32x4*)(wp + rb * 4);
            }
        }

        // ---- 32 recurrent steps ----
#pragma unroll 1
        for (int i = 0; i < 32; ++i) {
            const int t = t0 + i;
            const u32* hcur = hS1[t & 1];
            float a0 = 0.f, a1 = 0.f, a2 = 0.f, a3 = 0.f;
#pragma unroll
            for (int rb = 0; rb < 4; ++rb) {
                const u32x4 hq = *(const u32x4*)(hcur + (q << 4) + (((rb + q) & 3) << 2));
                a0 = fdot2_(Wq[0][rb].x, hq.x, a0); a0 = fdot2_(Wq[0][rb].y, hq.y, a0);
                a0 = fdot2_(Wq[0][rb].z, hq.z, a0); a0 = fdot2_(Wq[0][rb].w, hq.w, a0);
                a1 = fdot2_(Wq[1][rb].x, hq.x, a1); a1 = fdot2_(Wq[1][rb].y, hq.y, a1);
                a1 = fdot2_(Wq[1][rb].z, hq.z, a1); a1 = fdot2_(Wq[1][rb].w, hq.w, a1);
                a2 = fdot2_(Wq[2][rb].x, hq.x, a2); a2 = fdot2_(Wq[2][rb].y, hq.y, a2);
                a2 = fdot2_(Wq[2][rb].z, hq.z, a2); a2 = fdot2_(Wq[2][rb].w, hq.w, a2);
                a3 = fdot2_(Wq[3][rb].x, hq.x, a3); a3 = fdot2_(Wq[3][rb].y, hq.y, a3);
                a3 = fdot2_(Wq[3][rb].z, hq.z, a3); a3 = fdot2_(Wq[3][rb].w, hq.w, a3);
            }
            const float V = xpose4(a0, a1, a2, a3, q);
            const float a = V + xgS[i * 512 + (tid ^ ((i & 7) << 2))];
            const float act = fmaf(Ag, rcp_(1.f + ex2(a)), Cg);
            const float gi = dpp_mov(act, 0x00);
            const float gf = dpp_mov(act, 0x55);
            const float gg = dpp_mov(act, 0xAA);
            const float go = dpp_mov(act, 0xFF);
            c1 = fmaf(gf, c1, gi * gg);
            const float h = go * fmaf(-2.f, rcp_(1.f + ex2(K2L2E * c1)), 1.f);
            if (q == 0)
                ((u16*)hS1[(t + 1) & 1])[2 * hswz(u >> 1) + (u & 1)] =
                    __builtin_bit_cast(u16, (f16)h);

            // FC partial: quad-redundant h, wave-local reduce, no serial chain
            float pf = h * fcu025;
            pf = dpp_add(pf, 0xB1);    // xor1
            pf = dpp_add(pf, 0x4E);    // xor2
            pf = dpp_add(pf, 0x141);   // xor4 (half-mirror, quads uniform)
            pf = dpp_add(pf, 0x140);   // xor8 (row mirror) -> 16-row sums
            pf += __int_as_float(__builtin_amdgcn_ds_swizzle(__float_as_int(pf), 0x401F)); // xor16
            if ((lane & 31) == 0) fcP[i][wv * 2 + (lane >> 5)] = pf;
            __syncthreads();
        }

        // ---- chunk-end FC gather: 32 outputs ----
        if (tid < 32) {
            float s = 0.f;
#pragma unroll
            for (int r = 0; r < 4; ++r) {
                const float4 v = *(const float4*)&fcP[tid][r * 4];
                s += (v.x + v.y) + (v.z + v.w);
            }
            ob[t0 + tid] = s + fcbv;
        }
        // ordering: gather threads pass the next proj's __syncthreads before
        // any thread can write fcP again -> no extra barrier needed
    }
}

extern "C" void kernel_launch(void* const* d_in, const int* in_sizes, int n_in,
                              void* d_out, int out_size, void* d_ws, size_t ws_size,
                              hipStream_t stream)
{
    const float* x    = (const float*)d_in[0];
    const float* Wih0 = (const float*)d_in[1];
    const float* Whh0 = (const float*)d_in[2];
    const float* bih0 = (const float*)d_in[3];
    const float* bhh0 = (const float*)d_in[4];
    const float* Wih1 = (const float*)d_in[5];
    const float* Whh1 = (const float*)d_in[6];
    const float* bih1 = (const float*)d_in[7];
    const float* bhh1 = (const float*)d_in[8];
    const float* fcw  = (const float*)d_in[9];
    const float* fcb  = (const float*)d_in[10];
    float* out = (float*)d_out;

    f16* h0g  = (f16*)d_ws;                          // 256*1024*128 f16 = 64 MiB
    f16* Wpk0 = h0g + (size_t)256 * TT * HH;         // 128 KiB each
    f16* Wpk1 = Wpk0 + 512 * HH;
    f16* W1h  = Wpk1 + 512 * HH;
    f16* W1l  = W1h + 512 * HH;
    float* bx0 = (float*)(W1l + 512 * HH);
    float* wx0 = bx0 + 512;
    float* b1p = wx0 + 512;

    prep <<<512, 128, 0, stream>>>(Whh0, Whh1, Wih1, Wih0, bih0, bhh0, bih1, bhh1,
                                   Wpk0, Wpk1, W1h, W1l, bx0, wx0, b1p);
    lstm0<<<256, 512, 0, stream>>>(x, Wpk0, bx0, wx0, h0g);
    lstm1<<<256, 512, 0, stream>>>(h0g, Wpk1, W1h, W1l, b1p, fcw, fcb, out);
}